// Round 7
// baseline (614.301 us; speedup 1.0000x reference)
//
#include <hip/hip_runtime.h>
#include <hip/hip_bf16.h>

#define N_NODES 50000
#define N_EDGES 500000
constexpr int HID = 64;
constexpr int HC  = 256;   // HEADS*HID

typedef unsigned short u16;
typedef unsigned char u8;
typedef __attribute__((ext_vector_type(8))) __bf16 bf16x8;
typedef __attribute__((ext_vector_type(4))) float f32x4;
typedef __attribute__((ext_vector_type(2))) float f32x2;

__device__ __forceinline__ float b2f(u16 u) {
    union { unsigned int i; float f; } c; c.i = ((unsigned int)u) << 16; return c.f;
}
__device__ __forceinline__ u16 f2b(float f) {
    union { float f; unsigned int i; } c; c.f = f;
    unsigned int x = c.i;
    unsigned int lsb = (x >> 16) & 1u;
    x += 0x7fffu + lsb;
    return (u16)(x >> 16);
}
__device__ __forceinline__ float elu_f(float x) { return x > 0.f ? x : expm1f(x); }

// kv fp8 layout (scale 16, e4m3): group g (8B) = [k ch 4g..4g+3][v ch 4g..4g+3]
// lane l reads 8B at kv + node*512 + l*8.

// ---------------- init: zero cnt/cursor ----------------
__global__ __launch_bounds__(256) void init_kernel(int* __restrict__ cnt, int* __restrict__ cursor) {
    int i = blockIdx.x * 256 + threadIdx.x;
    if (i < N_NODES) { cnt[i] = 0; cursor[i] = 0; }
}

// ---------------- edge_index layout detect (int32 vs int64) ----------------
__global__ __launch_bounds__(256) void detect_kernel(const int* __restrict__ ei, int* __restrict__ flag) {
    __shared__ int s[4];
    int t = threadIdx.x;
    int nz = ei[2 * t + 1] != 0;
    unsigned long long m = __ballot(nz);
    if ((t & 63) == 0) s[t >> 6] = (m != 0ull) ? 1 : 0;
    __syncthreads();
    if (t == 0) flag[0] = s[0] | s[1] | s[2] | s[3];   // 1 => int32 layout
}

// ---------------- weight pre-conversion fp32 -> bf16 (once) ----------------
// w16 = [Wq 65536][Wk 65536][Wv 65536][Wsk 16384] in original flat order.
__global__ __launch_bounds__(256) void wcvt_kernel(const float* __restrict__ Wq, const float* __restrict__ Wk,
                                                   const float* __restrict__ Wv, const float* __restrict__ Wsk,
                                                   u16* __restrict__ w16) {
    int i = blockIdx.x * 256 + threadIdx.x;   // float4 index
    if (i >= 53248) return;
    const float* src; int off;
    if (i < 16384)      { src = Wq;  off = i; }
    else if (i < 32768) { src = Wk;  off = i - 16384; }
    else if (i < 49152) { src = Wv;  off = i - 32768; }
    else                { src = Wsk; off = i - 49152; }
    float4 v = ((const float4*)src)[off];
    ushort4 u; u.x = f2b(v.x); u.y = f2b(v.y); u.z = f2b(v.z); u.w = f2b(v.w);
    ((ushort4*)w16)[i] = u;
}

// ---------------- CSR build (counting sort by dst) ----------------
__global__ __launch_bounds__(256) void hist_kernel(const int* __restrict__ ei, const int* __restrict__ flag,
                                                   int* __restrict__ cnt) {
    int e = blockIdx.x * 256 + threadIdx.x;
    if (e < N_EDGES) {
        int d = flag[0] ? ei[N_EDGES + e] : ei[2 * N_EDGES + 2 * e];
        atomicAdd(&cnt[d], 1);
    }
}

__global__ __launch_bounds__(512) void scan1_kernel(const int* __restrict__ cnt,
                                                    int* __restrict__ row_start, int* __restrict__ bsum) {
    __shared__ int sc[512];
    int t = threadIdx.x;
    int i = blockIdx.x * 512 + t;
    int v = (i < N_NODES) ? cnt[i] : 0;
    sc[t] = v;
    __syncthreads();
    for (int off = 1; off < 512; off <<= 1) {
        int u = (t >= off) ? sc[t - off] : 0;
        __syncthreads();
        sc[t] += u;
        __syncthreads();
    }
    if (i < N_NODES) row_start[i] = sc[t] - v;
    if (t == 511) bsum[blockIdx.x] = sc[511];
}

__global__ __launch_bounds__(128) void scan2_kernel(int* __restrict__ bsum, int* __restrict__ row_start) {
    __shared__ int sc[128];
    const int NB = (N_NODES + 511) / 512;  // 98
    int t = threadIdx.x;
    int v = (t < NB) ? bsum[t] : 0;
    sc[t] = v;
    __syncthreads();
    for (int off = 1; off < 128; off <<= 1) {
        int u = (t >= off) ? sc[t - off] : 0;
        __syncthreads();
        sc[t] += u;
        __syncthreads();
    }
    if (t < NB) bsum[t] = sc[t] - v;
    if (t == 127) row_start[N_NODES] = sc[127];
}

__global__ __launch_bounds__(512) void scan3_kernel(int* __restrict__ row_start, const int* __restrict__ bsum) {
    int i = blockIdx.x * 512 + threadIdx.x;
    if (i < N_NODES) row_start[i] += bsum[blockIdx.x];
}

__global__ __launch_bounds__(256) void scatter_kernel(const int* __restrict__ ei, const int* __restrict__ flag,
                                const int* __restrict__ row_start, int* __restrict__ cursor,
                                int* __restrict__ csr_src) {
    int e = blockIdx.x * 256 + threadIdx.x;
    if (e < N_EDGES) {
        int isI32 = flag[0];
        int s = isI32 ? ei[e] : ei[2 * e];
        int d = isI32 ? ei[N_EDGES + e] : ei[2 * N_EDGES + 2 * e];
        int pos = row_start[d] + atomicAdd(&cursor[d], 1);
        csr_src[pos] = s;
    }
}

// ---------------- Encoder: 8->64 elu (VALU) -> 64->64 elu (MFMA) ----------------
__global__ __launch_bounds__(256) void encoder_kernel(const float* __restrict__ x,
                               const float* __restrict__ w1, const float* __restrict__ b1,
                               const float* __restrict__ w2, const float* __restrict__ b2,
                               float* __restrict__ h) {
    __shared__ float xs[64 * 9];
    __shared__ float w1s[64 * 9];
    __shared__ u16 t1s[64 * 72];
    __shared__ u16 w2s[64 * 72];
    __shared__ float b1s[64], b2s[64];
    int t = threadIdx.x;
    int m0 = blockIdx.x * 64;

    if (t < 128) {
        int row = t >> 1, c = (t & 1) * 4;
        float4 val = make_float4(0.f, 0.f, 0.f, 0.f);
        if (m0 + row < N_NODES) val = *(const float4*)(x + (size_t)(m0 + row) * 8 + c);
        *(float4*)&xs[row * 9 + c] = val;
    }
    if (t >= 128 && t < 256) {
        int p = t - 128;
        int row = p >> 1, c = (p & 1) * 4;
        float4 val = *(const float4*)(w1 + row * 8 + c);
        *(float4*)&w1s[row * 9 + c] = val;
    }
    #pragma unroll
    for (int r = 0; r < 4; ++r) {
        int p = t + r * 256; int row = p >> 4, kc = (p & 15) * 4;
        float4 val = *(const float4*)(w2 + row * 64 + kc);
        ushort4 u; u.x = f2b(val.x); u.y = f2b(val.y); u.z = f2b(val.z); u.w = f2b(val.w);
        *(ushort4*)&w2s[row * 72 + kc] = u;
    }
    if (t < 64) { b1s[t] = b1[t]; b2s[t] = b2[t]; }
    __syncthreads();

    {
        int j = t & 63, sub = t >> 6;
        #pragma unroll
        for (int g = 0; g < 16; ++g) {
            int node = g * 4 + sub;
            float acc = b1s[j];
            #pragma unroll
            for (int m = 0; m < 8; ++m) acc += xs[node * 9 + m] * w1s[j * 9 + m];
            t1s[node * 72 + j] = f2b(elu_f(acc));
        }
    }
    __syncthreads();

    int wave = t >> 6, lane = t & 63;
    int lrow = lane & 15, quad = lane >> 4;
    int m_off = wave * 16;
    bf16x8 a0 = *(const bf16x8*)&t1s[(m_off + lrow) * 72 + quad * 8];
    bf16x8 a1 = *(const bf16x8*)&t1s[(m_off + lrow) * 72 + 32 + quad * 8];
    #pragma unroll
    for (int nsub = 0; nsub < 4; ++nsub) {
        bf16x8 b0 = *(const bf16x8*)&w2s[(nsub * 16 + lrow) * 72 + quad * 8];
        bf16x8 b1v = *(const bf16x8*)&w2s[(nsub * 16 + lrow) * 72 + 32 + quad * 8];
        f32x4 acc = {0.f, 0.f, 0.f, 0.f};
        acc = __builtin_amdgcn_mfma_f32_16x16x32_bf16(a0, b0, acc, 0, 0, 0);
        acc = __builtin_amdgcn_mfma_f32_16x16x32_bf16(a1, b1v, acc, 0, 0, 0);
        int col = nsub * 16 + lrow;
        float bias = b2s[col];
        #pragma unroll
        for (int r = 0; r < 4; ++r) {
            int row = m0 + m_off + quad * 4 + r;
            if (row < N_NODES) h[(size_t)row * 64 + col] = elu_f(acc[r] + bias);
        }
    }
}

// ---------------- Projection: 64-row tile; B-frags direct from bf16 global;
// all outputs staged in LDS for coalesced 16B stores ----------------
__global__ __launch_bounds__(256) void proj_kernel(const float* __restrict__ h,
    const u16* __restrict__ wq16, const u16* __restrict__ wk16,
    const u16* __restrict__ wv16, const u16* __restrict__ wsk16,
    const float* __restrict__ bq, const float* __restrict__ bk,
    const float* __restrict__ bv, const float* __restrict__ bsk,
    int layer,
    u16* __restrict__ q, u8* __restrict__ kv, float* __restrict__ skip)
{
    __shared__ u16 as_tile[64 * 72];        // 9216 B
    __shared__ float poolf[4352];           // 17408 B staging pool (q / kv / skip)
    __shared__ float bias_s[64];
    __shared__ float bias_s2[64];
    u16* ot_h = (u16*)poolf;
    u8*  kbuf = (u8*)poolf;
    u8*  vbuf = (u8*)poolf + 4608;

    int t = threadIdx.x;
    int m0 = blockIdx.x * 64;

    // stage A (h rows, fp32 -> bf16)
    #pragma unroll
    for (int r = 0; r < 4; ++r) {
        int p = t + r * 256; int row = p >> 4, kc = (p & 15) * 4;
        float4 val = make_float4(0.f, 0.f, 0.f, 0.f);
        if (m0 + row < N_NODES) val = *(const float4*)(h + (size_t)(m0 + row) * 64 + kc);
        ushort4 u; u.x = f2b(val.x); u.y = f2b(val.y); u.z = f2b(val.z); u.w = f2b(val.w);
        *(ushort4*)&as_tile[row * 72 + kc] = u;
    }
    __syncthreads();

    int wave = t >> 6, lane = t & 63;
    int lrow = lane & 15, quad = lane >> 4;
    int m_off = wave * 16;
    bf16x8 a0 = *(const bf16x8*)&as_tile[(m_off + lrow) * 72 + quad * 8];
    bf16x8 a1 = *(const bf16x8*)&as_tile[(m_off + lrow) * 72 + 32 + quad * 8];

    const u16* Wq16  = wq16  + (size_t)layer * HC * HID;
    const u16* Wk16  = wk16  + (size_t)layer * HC * HID;
    const u16* Wv16  = wv16  + (size_t)layer * HC * HID;
    const u16* Wsk16 = wsk16 + (size_t)layer * HID * HID;

    // ---- Q tiles (bf16 out, coalesced) ----
    for (int ct = 0; ct < 4; ++ct) {
        int cbase = ct * 64;
        if (t < 64) bias_s[t] = bq[layer * HC + cbase + t];
        __syncthreads();   // bias ready; pool free from previous phase
        #pragma unroll
        for (int nsub = 0; nsub < 4; ++nsub) {
            const u16* wrow = Wq16 + (size_t)(cbase + nsub * 16 + lrow) * 64 + quad * 8;
            bf16x8 b0 = *(const bf16x8*)wrow;
            bf16x8 b1 = *(const bf16x8*)(wrow + 32);
            f32x4 acc = {0.f, 0.f, 0.f, 0.f};
            acc = __builtin_amdgcn_mfma_f32_16x16x32_bf16(a0, b0, acc, 0, 0, 0);
            acc = __builtin_amdgcn_mfma_f32_16x16x32_bf16(a1, b1, acc, 0, 0, 0);
            float bias = bias_s[nsub * 16 + lrow];
            #pragma unroll
            for (int r = 0; r < 4; ++r)
                ot_h[(m_off + quad * 4 + r) * 72 + nsub * 16 + lrow] = f2b(acc[r] + bias);
        }
        __syncthreads();
        #pragma unroll
        for (int it = 0; it < 2; ++it) {
            int p = t + it * 256; int row = p >> 3, ch = p & 7;
            int grow = m0 + row;
            if (grow < N_NODES) {
                uint4 val = *(const uint4*)&ot_h[row * 72 + ch * 8];
                *(uint4*)(q + (size_t)grow * 256 + cbase + ch * 8) = val;
            }
        }
    }

    // ---- KV pairs (fp8, interleaved, coalesced) ----
    for (int ct = 0; ct < 4; ++ct) {
        int cbase = ct * 64;
        if (t < 64) bias_s[t] = bk[layer * HC + cbase + t];
        else if (t < 128) bias_s2[t - 64] = bv[layer * HC + cbase + (t - 64)];
        __syncthreads();
        #pragma unroll
        for (int nsub = 0; nsub < 4; ++nsub) {
            const u16* wrow = Wk16 + (size_t)(cbase + nsub * 16 + lrow) * 64 + quad * 8;
            bf16x8 b0 = *(const bf16x8*)wrow;
            bf16x8 b1 = *(const bf16x8*)(wrow + 32);
            f32x4 acc = {0.f, 0.f, 0.f, 0.f};
            acc = __builtin_amdgcn_mfma_f32_16x16x32_bf16(a0, b0, acc, 0, 0, 0);
            acc = __builtin_amdgcn_mfma_f32_16x16x32_bf16(a1, b1, acc, 0, 0, 0);
            float bias = bias_s[nsub * 16 + lrow];
            #pragma unroll
            for (int r = 0; r < 4; ++r) {
                float f = (acc[r] + bias) * 16.f;
                int pk = __builtin_amdgcn_cvt_pk_fp8_f32(f, f, 0, false);
                kbuf[(m_off + quad * 4 + r) * 72 + nsub * 16 + lrow] = (u8)(pk & 0xff);
            }
        }
        #pragma unroll
        for (int nsub = 0; nsub < 4; ++nsub) {
            const u16* wrow = Wv16 + (size_t)(cbase + nsub * 16 + lrow) * 64 + quad * 8;
            bf16x8 b0 = *(const bf16x8*)wrow;
            bf16x8 b1 = *(const bf16x8*)(wrow + 32);
            f32x4 acc = {0.f, 0.f, 0.f, 0.f};
            acc = __builtin_amdgcn_mfma_f32_16x16x32_bf16(a0, b0, acc, 0, 0, 0);
            acc = __builtin_amdgcn_mfma_f32_16x16x32_bf16(a1, b1, acc, 0, 0, 0);
            float bias = bias_s2[nsub * 16 + lrow];
            #pragma unroll
            for (int r = 0; r < 4; ++r) {
                float f = (acc[r] + bias) * 16.f;
                int pk = __builtin_amdgcn_cvt_pk_fp8_f32(f, f, 0, false);
                vbuf[(m_off + quad * 4 + r) * 72 + nsub * 16 + lrow] = (u8)(pk & 0xff);
            }
        }
        __syncthreads();
        #pragma unroll
        for (int it = 0; it < 2; ++it) {
            int p = t + it * 256; int row = p >> 3, ch = p & 7;
            int grow = m0 + row;
            if (grow < N_NODES) {
                unsigned int k01 = *(const unsigned int*)&kbuf[row * 72 + ch * 8];
                unsigned int k23 = *(const unsigned int*)&kbuf[row * 72 + ch * 8 + 4];
                unsigned int v01 = *(const unsigned int*)&vbuf[row * 72 + ch * 8];
                unsigned int v23 = *(const unsigned int*)&vbuf[row * 72 + ch * 8 + 4];
                uint4 val; val.x = k01; val.y = v01; val.z = k23; val.w = v23;
                *(uint4*)(kv + (size_t)grow * 512 + cbase * 2 + ch * 16) = val;
            }
        }
    }

    // ---- skip tile (fp32, coalesced) ----
    {
        float* ot_f = poolf;
        if (t < 64) bias_s[t] = bsk[layer * HID + t];
        __syncthreads();
        #pragma unroll
        for (int nsub = 0; nsub < 4; ++nsub) {
            const u16* wrow = Wsk16 + (size_t)(nsub * 16 + lrow) * 64 + quad * 8;
            bf16x8 b0 = *(const bf16x8*)wrow;
            bf16x8 b1 = *(const bf16x8*)(wrow + 32);
            f32x4 acc = {0.f, 0.f, 0.f, 0.f};
            acc = __builtin_amdgcn_mfma_f32_16x16x32_bf16(a0, b0, acc, 0, 0, 0);
            acc = __builtin_amdgcn_mfma_f32_16x16x32_bf16(a1, b1, acc, 0, 0, 0);
            float bias = bias_s[nsub * 16 + lrow];
            #pragma unroll
            for (int r = 0; r < 4; ++r)
                ot_f[(m_off + quad * 4 + r) * 68 + nsub * 16 + lrow] = acc[r] + bias;
        }
        __syncthreads();
        int row = t >> 2, c4 = (t & 3) * 16;
        int grow = m0 + row;
        if (grow < N_NODES) {
            #pragma unroll
            for (int j = 0; j < 4; ++j)
                *(float4*)(skip + (size_t)grow * 64 + c4 + j * 4) = *(const float4*)&ot_f[row * 68 + c4 + j * 4];
        }
    }
}

// ---------------- Attention: one wave per dst node, CSR, fp8 kv, unroll 8 ----------------
__global__ __launch_bounds__(256) void attn_kernel(
    const u16* __restrict__ q, const u8* __restrict__ kv,
    const float* __restrict__ skip,
    const int* __restrict__ row_start, const int* __restrict__ csr_src,
    float* __restrict__ hout)
{
    int wave = threadIdx.x >> 6;
    int lane = threadIdx.x & 63;
    int n = blockIdx.x * 4 + wave;
    if (n >= N_NODES) return;
    ushort4 q4 = ((const ushort4*)(q + (size_t)n * 256))[lane];
    float qf0 = b2f(q4.x), qf1 = b2f(q4.y), qf2 = b2f(q4.z), qf3 = b2f(q4.w);
    const u8* kvl = kv + lane * 8;
    float l = 0.f;
    float a0 = 0.f, a1 = 0.f, a2 = 0.f, a3 = 0.f;
    int e0 = row_start[n], e1 = row_start[n + 1];
    for (int e = e0; e < e1; e += 8) {
        int rem = e1 - e;   // >= 1
        int s[8];
        #pragma unroll
        for (int j = 0; j < 8; ++j) {
            int jj = j < rem ? j : rem - 1;
            s[j] = csr_src[e + jj];
        }
        uint2 c[8];
        #pragma unroll
        for (int j = 0; j < 8; ++j) c[j] = *(const uint2*)(kvl + (size_t)s[j] * 512);
        float p[8];
        #pragma unroll
        for (int j = 0; j < 8; ++j) {
            f32x2 ka = __builtin_amdgcn_cvt_pk_f32_fp8(c[j].x, false);
            f32x2 kb = __builtin_amdgcn_cvt_pk_f32_fp8(c[j].x, true);
            p[j] = qf0 * ka.x + qf1 * ka.y + qf2 * kb.x + qf3 * kb.y;
        }
        #pragma unroll
        for (int j = 0; j < 8; ++j) p[j] += __shfl_xor(p[j], 1);
        #pragma unroll
        for (int j = 0; j < 8; ++j) p[j] += __shfl_xor(p[j], 2);
        #pragma unroll
        for (int j = 0; j < 8; ++j) p[j] += __shfl_xor(p[j], 4);
        #pragma unroll
        for (int j = 0; j < 8; ++j) p[j] += __shfl_xor(p[j], 8);
        const float S = 0.0078125f;  // 1/(8*16)
        float w[8];
        w[0] = __expf(p[0] * S);
        #pragma unroll
        for (int j = 1; j < 8; ++j) w[j] = j < rem ? __expf(p[j] * S) : 0.f;
        float ls = 0.f;
        #pragma unroll
        for (int j = 0; j < 8; ++j) ls += w[j];
        l += ls;
        #pragma unroll
        for (int j = 0; j < 8; ++j) {
            f32x2 va = __builtin_amdgcn_cvt_pk_f32_fp8(c[j].y, false);
            f32x2 vb = __builtin_amdgcn_cvt_pk_f32_fp8(c[j].y, true);
            a0 += w[j] * va.x; a1 += w[j] * va.y;
            a2 += w[j] * vb.x; a3 += w[j] * vb.y;
        }
    }
    float inv = l > 0.f ? 1.f / l : 0.f;
    a0 *= inv; a1 *= inv; a2 *= inv; a3 *= inv;
    a0 += __shfl_xor(a0, 16); a0 += __shfl_xor(a0, 32);
    a1 += __shfl_xor(a1, 16); a1 += __shfl_xor(a1, 32);
    a2 += __shfl_xor(a2, 16); a2 += __shfl_xor(a2, 32);
    a3 += __shfl_xor(a3, 16); a3 += __shfl_xor(a3, 32);
    if ((lane >> 4) == 0) {
        const float OS = 0.015625f;  // 0.25 (head mean) * 1/16 (v scale)
        float4 sk = ((const float4*)(skip + (size_t)n * 64))[lane];
        float4 o;
        o.x = elu_f(OS * a0 + sk.x);
        o.y = elu_f(OS * a1 + sk.y);
        o.z = elu_f(OS * a2 + sk.z);
        o.w = elu_f(OS * a3 + sk.w);
        ((float4*)(hout + (size_t)n * 64))[lane] = o;
    }
}

// ---------------- Output MLP: 64->64 elu (MFMA) ->32 elu (MFMA) ->8 (VALU) ----------------
__global__ __launch_bounds__(256) void mlp_kernel(const float* __restrict__ h,
    const float* __restrict__ w1, const float* __restrict__ b1,
    const float* __restrict__ w2, const float* __restrict__ b2,
    const float* __restrict__ w3, const float* __restrict__ b3,
    float* __restrict__ out)
{
    __shared__ u16 hs[64 * 72];
    __shared__ u16 w1s[64 * 72];
    __shared__ u16 t1s[64 * 72];
    __shared__ u16 w2s[32 * 72];
    __shared__ float t2s[64 * 33];
    __shared__ float w3s[8 * 33];
    __shared__ float b1s[64], b2s[32], b3s[8];
    int t = threadIdx.x;
    int m0 = blockIdx.x * 64;

    #pragma unroll
    for (int r = 0; r < 4; ++r) {
        int p = t + r * 256; int row = p >> 4, kc = (p & 15) * 4;
        float4 val = make_float4(0.f, 0.f, 0.f, 0.f);
        if (m0 + row < N_NODES) val = *(const float4*)(h + (size_t)(m0 + row) * 64 + kc);
        ushort4 u; u.x = f2b(val.x); u.y = f2b(val.y); u.z = f2b(val.z); u.w = f2b(val.w);
        *(ushort4*)&hs[row * 72 + kc] = u;
    }
    #pragma unroll
    for (int r = 0; r < 4; ++r) {
        int p = t + r * 256; int row = p >> 4, kc = (p & 15) * 4;
        float4 val = *(const float4*)(w1 + row * 64 + kc);
        ushort4 u; u.x = f2b(val.x); u.y = f2b(val.y); u.z = f2b(val.z); u.w = f2b(val.w);
        *(ushort4*)&w1s[row * 72 + kc] = u;
    }
    #pragma unroll
    for (int r = 0; r < 2; ++r) {
        int p = t + r * 256; int row = p >> 4, kc = (p & 15) * 4;
        float4 val = *(const float4*)(w2 + row * 64 + kc);
        ushort4 u; u.x = f2b(val.x); u.y = f2b(val.y); u.z = f2b(val.z); u.w = f2b(val.w);
        *(ushort4*)&w2s[row * 72 + kc] = u;
    }
    if (t < 8 * 32) { int r = t >> 5, c = t & 31; w3s[r * 33 + c] = w3[t]; }
    if (t < 64) b1s[t] = b1[t];
    if (t >= 64 && t < 96) b2s[t - 64] = b2[t - 64];
    if (t >= 96 && t < 104) b3s[t - 96] = b3[t - 96];
    __syncthreads();

    int wave = t >> 6, lane = t & 63;
    int lrow = lane & 15, quad = lane >> 4;
    int m_off = wave * 16;

    {
        bf16x8 a0 = *(const bf16x8*)&hs[(m_off + lrow) * 72 + quad * 8];
        bf16x8 a1 = *(const bf16x8*)&hs[(m_off + lrow) * 72 + 32 + quad * 8];
        #pragma unroll
        for (int nsub = 0; nsub < 4; ++nsub) {
            bf16x8 b0 = *(const bf16x8*)&w1s[(nsub * 16 + lrow) * 72 + quad * 8];
            bf16x8 b1v = *(const bf16x8*)&w1s[(nsub * 16 + lrow) * 72 + 32 + quad * 8];
            f32x4 acc = {0.f, 0.f, 0.f, 0.f};
            acc = __builtin_amdgcn_mfma_f32_16x16x32_bf16(a0, b0, acc, 0, 0, 0);
            acc = __builtin_amdgcn_mfma_f32_16x16x32_bf16(a1, b1v, acc, 0, 0, 0);
            int col = nsub * 16 + lrow;
            float bias = b1s[col];
            #pragma unroll
            for (int r = 0; r < 4; ++r) {
                int row = m_off + quad * 4 + r;
                t1s[row * 72 + col] = f2b(elu_f(acc[r] + bias));
            }
        }
    }
    __syncthreads();

    {
        bf16x8 a0 = *(const bf16x8*)&t1s[(m_off + lrow) * 72 + quad * 8];
        bf16x8 a1 = *(const bf16x8*)&t1s[(m_off + lrow) * 72 + 32 + quad * 8];
        #pragma unroll
        for (int nsub = 0; nsub < 2; ++nsub) {
            bf16x8 b0 = *(const bf16x8*)&w2s[(nsub * 16 + lrow) * 72 + quad * 8];
            bf16x8 b1v = *(const bf16x8*)&w2s[(nsub * 16 + lrow) * 72 + 32 + quad * 8];
            f32x4 acc = {0.f, 0.f, 0.f, 0.f};
            acc = __builtin_amdgcn_mfma_f32_16x16x32_bf16(a0, b0, acc, 0, 0, 0);
            acc = __builtin_amdgcn_mfma_f32_16x16x32_bf16(a1, b1v, acc, 0, 0, 0);
            int col = nsub * 16 + lrow;
            float bias = b2s[col];
            #pragma unroll
            for (int r = 0; r < 4; ++r) {
                int row = m_off + quad * 4 + r;
                t2s[row * 33 + col] = elu_f(acc[r] + bias);
            }
        }
    }
    __syncthreads();

    #pragma unroll
    for (int r = 0; r < 2; ++r) {
        int idx = t + r * 256;
        int node = idx >> 3, j = idx & 7;
        int row = m0 + node;
        if (row < N_NODES) {
            float acc = b3s[j];
            #pragma unroll
            for (int kk = 0; kk < 32; ++kk) acc += t2s[node * 33 + kk] * w3s[j * 33 + kk];
            out[(size_t)row * 8 + j] = acc;
        }
    }
}

extern "C" void kernel_launch(void* const* d_in, const int* in_sizes, int n_in,
                              void* d_out, int out_size, void* d_ws, size_t ws_size,
                              hipStream_t stream) {
    (void)in_sizes; (void)n_in; (void)out_size; (void)ws_size;
    const float* x   = (const float*)d_in[0];
    const int* ei    = (const int*)d_in[1];
    const float* ew1 = (const float*)d_in[2];
    const float* eb1 = (const float*)d_in[3];
    const float* ew2 = (const float*)d_in[4];
    const float* eb2 = (const float*)d_in[5];
    const float* Wq  = (const float*)d_in[6];
    const float* bq  = (const float*)d_in[7];
    const float* Wk  = (const float*)d_in[8];
    const float* bk  = (const float*)d_in[9];
    const float* Wv  = (const float*)d_in[10];
    const float* bv  = (const float*)d_in[11];
    const float* Wsk = (const float*)d_in[12];
    const float* bsk = (const float*)d_in[13];
    const float* ow1 = (const float*)d_in[14];
    const float* ob1 = (const float*)d_in[15];
    const float* ow2 = (const float*)d_in[16];
    const float* ob2 = (const float*)d_in[17];
    const float* ow3 = (const float*)d_in[18];
    const float* ob3 = (const float*)d_in[19];

    char* ws = (char*)d_ws;
    size_t off = 0;
    auto alloc = [&](size_t bytes) -> void* {
        void* p = ws + off;
        off += (bytes + 255) & ~(size_t)255;
        return p;
    };
    float* h0    = (float*)alloc((size_t)N_NODES * 64 * 4);
    float* h1    = (float*)alloc((size_t)N_NODES * 64 * 4);
    u16*   q     = (u16*)  alloc((size_t)N_NODES * 256 * 2);
    u8*    kv    = (u8*)   alloc((size_t)N_NODES * 512);
    float* skp   = (float*)alloc((size_t)N_NODES * 64 * 4);
    u16*   w16   = (u16*)  alloc((size_t)212992 * 2);
    int*   cnt   = (int*)  alloc((size_t)N_NODES * 4);
    int*   cursor= (int*)  alloc((size_t)N_NODES * 4);
    int*   rowst = (int*)  alloc((size_t)(N_NODES + 1) * 4);
    int*   csr   = (int*)  alloc((size_t)N_EDGES * 4);
    int*   bsum  = (int*)  alloc(512);
    int*   flag  = (int*)  alloc(256);

    u16* wq16  = w16;
    u16* wk16  = w16 + 65536;
    u16* wv16  = w16 + 131072;
    u16* wsk16 = w16 + 196608;

    const int NB = (N_NODES + 511) / 512;   // 98 scan blocks

    init_kernel<<<(N_NODES + 255) / 256, 256, 0, stream>>>(cnt, cursor);
    detect_kernel<<<1, 256, 0, stream>>>(ei, flag);
    wcvt_kernel<<<208, 256, 0, stream>>>(Wq, Wk, Wv, Wsk, w16);
    hist_kernel<<<(N_EDGES + 255) / 256, 256, 0, stream>>>(ei, flag, cnt);
    scan1_kernel<<<NB, 512, 0, stream>>>(cnt, rowst, bsum);
    scan2_kernel<<<1, 128, 0, stream>>>(bsum, rowst);
    scan3_kernel<<<NB, 512, 0, stream>>>(rowst, bsum);
    scatter_kernel<<<(N_EDGES + 255) / 256, 256, 0, stream>>>(ei, flag, rowst, cursor, csr);

    encoder_kernel<<<(N_NODES + 63) / 64, 256, 0, stream>>>(x, ew1, eb1, ew2, eb2, h0);

    float* hin = h0;
    float* hout = h1;
    for (int l = 0; l < 4; ++l) {
        proj_kernel<<<(N_NODES + 63) / 64, 256, 0, stream>>>(hin, wq16, wk16, wv16, wsk16,
                                                             bq, bk, bv, bsk, l, q, kv, skp);
        attn_kernel<<<(N_NODES + 3) / 4, 256, 0, stream>>>(q, kv, skp, rowst, csr, hout);
        float* tmp = hin; hin = hout; hout = tmp;
    }

    mlp_kernel<<<(N_NODES + 63) / 64, 256, 0, stream>>>(hin, ow1, ob1, ow2, ob2, ow3, ob3, (float*)d_out);
}

// Round 8
// 471.459 us; speedup vs baseline: 1.3030x; 1.3030x over previous
//
#include <hip/hip_runtime.h>
#include <hip/hip_bf16.h>

#define N_NODES 50000
#define N_EDGES 500000
constexpr int HID = 64;
constexpr int HC  = 256;   // HEADS*HID

typedef unsigned short u16;
typedef unsigned char u8;
typedef __attribute__((ext_vector_type(8))) __bf16 bf16x8;
typedef __attribute__((ext_vector_type(4))) float f32x4;
typedef __attribute__((ext_vector_type(2))) float f32x2;

__device__ __forceinline__ float b2f(u16 u) {
    union { unsigned int i; float f; } c; c.i = ((unsigned int)u) << 16; return c.f;
}
__device__ __forceinline__ u16 f2b(float f) {
    union { float f; unsigned int i; } c; c.f = f;
    unsigned int x = c.i;
    unsigned int lsb = (x >> 16) & 1u;
    x += 0x7fffu + lsb;
    return (u16)(x >> 16);
}
__device__ __forceinline__ float elu_f(float x) { return x > 0.f ? x : expm1f(x); }

// kv fp8 layout (scale 16, e4m3): group g (8B) = [k ch 4g..4g+3][v ch 4g..4g+3]
// lane l reads 8B at kv + node*512 + l*8.

// ---------------- init: zero cnt/cursor ----------------
__global__ __launch_bounds__(256) void init_kernel(int* __restrict__ cnt, int* __restrict__ cursor) {
    int i = blockIdx.x * 256 + threadIdx.x;
    if (i < N_NODES) { cnt[i] = 0; cursor[i] = 0; }
}

// ---------------- edge_index layout detect (int32 vs int64) ----------------
__global__ __launch_bounds__(256) void detect_kernel(const int* __restrict__ ei, int* __restrict__ flag) {
    __shared__ int s[4];
    int t = threadIdx.x;
    int nz = ei[2 * t + 1] != 0;
    unsigned long long m = __ballot(nz);
    if ((t & 63) == 0) s[t >> 6] = (m != 0ull) ? 1 : 0;
    __syncthreads();
    if (t == 0) flag[0] = s[0] | s[1] | s[2] | s[3];   // 1 => int32 layout
}

// ---------------- weight pre-conversion fp32 -> bf16 (once) ----------------
__global__ __launch_bounds__(256) void wcvt_kernel(const float* __restrict__ Wq, const float* __restrict__ Wk,
                                                   const float* __restrict__ Wv, const float* __restrict__ Wsk,
                                                   u16* __restrict__ w16) {
    int i = blockIdx.x * 256 + threadIdx.x;   // float4 index
    if (i >= 53248) return;
    const float* src; int off;
    if (i < 16384)      { src = Wq;  off = i; }
    else if (i < 32768) { src = Wk;  off = i - 16384; }
    else if (i < 49152) { src = Wv;  off = i - 32768; }
    else                { src = Wsk; off = i - 49152; }
    float4 v = ((const float4*)src)[off];
    ushort4 u; u.x = f2b(v.x); u.y = f2b(v.y); u.z = f2b(v.z); u.w = f2b(v.w);
    ((ushort4*)w16)[i] = u;
}

// ---------------- CSR build (counting sort by dst) ----------------
__global__ __launch_bounds__(256) void hist_kernel(const int* __restrict__ ei, const int* __restrict__ flag,
                                                   int* __restrict__ cnt) {
    int e = blockIdx.x * 256 + threadIdx.x;
    if (e < N_EDGES) {
        int d = flag[0] ? ei[N_EDGES + e] : ei[2 * N_EDGES + 2 * e];
        atomicAdd(&cnt[d], 1);
    }
}

__global__ __launch_bounds__(512) void scan1_kernel(const int* __restrict__ cnt,
                                                    int* __restrict__ row_start, int* __restrict__ bsum) {
    __shared__ int sc[512];
    int t = threadIdx.x;
    int i = blockIdx.x * 512 + t;
    int v = (i < N_NODES) ? cnt[i] : 0;
    sc[t] = v;
    __syncthreads();
    for (int off = 1; off < 512; off <<= 1) {
        int u = (t >= off) ? sc[t - off] : 0;
        __syncthreads();
        sc[t] += u;
        __syncthreads();
    }
    if (i < N_NODES) row_start[i] = sc[t] - v;
    if (t == 511) bsum[blockIdx.x] = sc[511];
}

__global__ __launch_bounds__(128) void scan2_kernel(int* __restrict__ bsum, int* __restrict__ row_start) {
    __shared__ int sc[128];
    const int NB = (N_NODES + 511) / 512;  // 98
    int t = threadIdx.x;
    int v = (t < NB) ? bsum[t] : 0;
    sc[t] = v;
    __syncthreads();
    for (int off = 1; off < 128; off <<= 1) {
        int u = (t >= off) ? sc[t - off] : 0;
        __syncthreads();
        sc[t] += u;
        __syncthreads();
    }
    if (t < NB) bsum[t] = sc[t] - v;
    if (t == 127) row_start[N_NODES] = sc[127];
}

__global__ __launch_bounds__(512) void scan3_kernel(int* __restrict__ row_start, const int* __restrict__ bsum) {
    int i = blockIdx.x * 512 + threadIdx.x;
    if (i < N_NODES) row_start[i] += bsum[blockIdx.x];
}

__global__ __launch_bounds__(256) void scatter_kernel(const int* __restrict__ ei, const int* __restrict__ flag,
                                const int* __restrict__ row_start, int* __restrict__ cursor,
                                int* __restrict__ csr_src) {
    int e = blockIdx.x * 256 + threadIdx.x;
    if (e < N_EDGES) {
        int isI32 = flag[0];
        int s = isI32 ? ei[e] : ei[2 * e];
        int d = isI32 ? ei[N_EDGES + e] : ei[2 * N_EDGES + 2 * e];
        int pos = row_start[d] + atomicAdd(&cursor[d], 1);
        csr_src[pos] = s;
    }
}

// ---------------- Encoder: 8->64 elu (VALU) -> 64->64 elu (MFMA) ----------------
__global__ __launch_bounds__(256) void encoder_kernel(const float* __restrict__ x,
                               const float* __restrict__ w1, const float* __restrict__ b1,
                               const float* __restrict__ w2, const float* __restrict__ b2,
                               float* __restrict__ h) {
    __shared__ float xs[64 * 9];
    __shared__ float w1s[64 * 9];
    __shared__ u16 t1s[64 * 72];
    __shared__ u16 w2s[64 * 72];
    __shared__ float b1s[64], b2s[64];
    int t = threadIdx.x;
    int m0 = blockIdx.x * 64;

    if (t < 128) {
        int row = t >> 1, c = (t & 1) * 4;
        float4 val = make_float4(0.f, 0.f, 0.f, 0.f);
        if (m0 + row < N_NODES) val = *(const float4*)(x + (size_t)(m0 + row) * 8 + c);
        *(float4*)&xs[row * 9 + c] = val;
    }
    if (t >= 128 && t < 256) {
        int p = t - 128;
        int row = p >> 1, c = (p & 1) * 4;
        float4 val = *(const float4*)(w1 + row * 8 + c);
        *(float4*)&w1s[row * 9 + c] = val;
    }
    #pragma unroll
    for (int r = 0; r < 4; ++r) {
        int p = t + r * 256; int row = p >> 4, kc = (p & 15) * 4;
        float4 val = *(const float4*)(w2 + row * 64 + kc);
        ushort4 u; u.x = f2b(val.x); u.y = f2b(val.y); u.z = f2b(val.z); u.w = f2b(val.w);
        *(ushort4*)&w2s[row * 72 + kc] = u;
    }
    if (t < 64) { b1s[t] = b1[t]; b2s[t] = b2[t]; }
    __syncthreads();

    {
        int j = t & 63, sub = t >> 6;
        #pragma unroll
        for (int g = 0; g < 16; ++g) {
            int node = g * 4 + sub;
            float acc = b1s[j];
            #pragma unroll
            for (int m = 0; m < 8; ++m) acc += xs[node * 9 + m] * w1s[j * 9 + m];
            t1s[node * 72 + j] = f2b(elu_f(acc));
        }
    }
    __syncthreads();

    int wave = t >> 6, lane = t & 63;
    int lrow = lane & 15, quad = lane >> 4;
    int m_off = wave * 16;
    bf16x8 a0 = *(const bf16x8*)&t1s[(m_off + lrow) * 72 + quad * 8];
    bf16x8 a1 = *(const bf16x8*)&t1s[(m_off + lrow) * 72 + 32 + quad * 8];
    #pragma unroll
    for (int nsub = 0; nsub < 4; ++nsub) {
        bf16x8 b0 = *(const bf16x8*)&w2s[(nsub * 16 + lrow) * 72 + quad * 8];
        bf16x8 b1v = *(const bf16x8*)&w2s[(nsub * 16 + lrow) * 72 + 32 + quad * 8];
        f32x4 acc = {0.f, 0.f, 0.f, 0.f};
        acc = __builtin_amdgcn_mfma_f32_16x16x32_bf16(a0, b0, acc, 0, 0, 0);
        acc = __builtin_amdgcn_mfma_f32_16x16x32_bf16(a1, b1v, acc, 0, 0, 0);
        int col = nsub * 16 + lrow;
        float bias = b2s[col];
        #pragma unroll
        for (int r = 0; r < 4; ++r) {
            int row = m0 + m_off + quad * 4 + r;
            if (row < N_NODES) h[(size_t)row * 64 + col] = elu_f(acc[r] + bias);
        }
    }
}

// ---------------- Projection: operand-swapped MFMA (lane owns 4 consecutive
// output channels of one node) + LDS staging + coalesced flushes ----------------
__global__ __launch_bounds__(256) void proj_kernel(const float* __restrict__ h,
    const u16* __restrict__ wq16, const u16* __restrict__ wk16,
    const u16* __restrict__ wv16, const u16* __restrict__ wsk16,
    const float* __restrict__ bq, const float* __restrict__ bk,
    const float* __restrict__ bv, const float* __restrict__ bsk,
    int layer,
    u16* __restrict__ q, u8* __restrict__ kv, float* __restrict__ skip)
{
    __shared__ u16 as_tile[64 * 72];     // h tile bf16 (B operand: node frags)
    __shared__ u16 ws_tile[64 * 72];     // weight tile bf16 (A operand)
    __shared__ float pool[64 * 68];      // 17408 B: qst u16[64*72] / kvst u8[64*144] / skst f32[64*68]
    u16* qst  = (u16*)pool;
    u8*  kvst = (u8*)pool;
    float* skst = pool;

    int t = threadIdx.x;
    int m0 = blockIdx.x * 64;

    // stage A (h rows, fp32 -> bf16)
    #pragma unroll
    for (int r = 0; r < 4; ++r) {
        int p = t + r * 256; int row = p >> 4, kc = (p & 15) * 4;
        float4 val = make_float4(0.f, 0.f, 0.f, 0.f);
        if (m0 + row < N_NODES) val = *(const float4*)(h + (size_t)(m0 + row) * 64 + kc);
        ushort4 u; u.x = f2b(val.x); u.y = f2b(val.y); u.z = f2b(val.z); u.w = f2b(val.w);
        *(ushort4*)&as_tile[row * 72 + kc] = u;
    }
    __syncthreads();

    int wave = t >> 6, lane = t & 63;
    int lrow = lane & 15, quad = lane >> 4;
    // h fragment (B operand): lane&15 = node within this wave's 16-node block
    bf16x8 a0 = *(const bf16x8*)&as_tile[(wave * 16 + lrow) * 72 + quad * 8];
    bf16x8 a1 = *(const bf16x8*)&as_tile[(wave * 16 + lrow) * 72 + 32 + quad * 8];

    const u16* Wq16  = wq16  + (size_t)layer * HC * HID;
    const u16* Wk16  = wk16  + (size_t)layer * HC * HID;
    const u16* Wv16  = wv16  + (size_t)layer * HC * HID;
    const u16* Wsk16 = wsk16 + (size_t)layer * HID * HID;
    const float* bqL  = bq  + layer * HC;
    const float* bkL  = bk  + layer * HC;
    const float* bvL  = bv  + layer * HC;
    const float* bskL = bsk + layer * HID;

    int nl = wave * 16 + lrow;          // node local index owned by this lane
    int grow_l = m0 + nl;

    // ---- Q tiles ----
    for (int ct = 0; ct < 4; ++ct) {
        int cbase = ct * 64;
        __syncthreads();   // previous flush done; ws_tile free
        #pragma unroll
        for (int it = 0; it < 2; ++it) {
            int p = t + it * 256; int row = p >> 3, kc = (p & 7) * 8;
            *(uint4*)&ws_tile[row * 72 + kc] = *(const uint4*)(Wq16 + (size_t)(cbase + row) * 64 + kc);
        }
        __syncthreads();
        #pragma unroll
        for (int nsub = 0; nsub < 4; ++nsub) {
            bf16x8 w0 = *(const bf16x8*)&ws_tile[(nsub * 16 + lrow) * 72 + quad * 8];
            bf16x8 w1 = *(const bf16x8*)&ws_tile[(nsub * 16 + lrow) * 72 + 32 + quad * 8];
            f32x4 acc = {0.f, 0.f, 0.f, 0.f};
            acc = __builtin_amdgcn_mfma_f32_16x16x32_bf16(w0, a0, acc, 0, 0, 0);
            acc = __builtin_amdgcn_mfma_f32_16x16x32_bf16(w1, a1, acc, 0, 0, 0);
            float4 b4 = *(const float4*)(bqL + cbase + nsub * 16 + quad * 4);
            ushort4 o;
            o.x = f2b(acc[0] + b4.x); o.y = f2b(acc[1] + b4.y);
            o.z = f2b(acc[2] + b4.z); o.w = f2b(acc[3] + b4.w);
            *(ushort4*)&qst[nl * 72 + nsub * 16 + quad * 4] = o;
        }
        __syncthreads();
        #pragma unroll
        for (int it = 0; it < 2; ++it) {
            int p = t + it * 256; int row = p >> 3, ch = p & 7;
            int grow = m0 + row;
            if (grow < N_NODES)
                *(uint4*)(q + (size_t)grow * 256 + cbase + ch * 8) = *(const uint4*)&qst[row * 72 + ch * 8];
        }
    }

    // ---- KV tiles (k pass then v pass into interleaved staging, one flush) ----
    for (int ct = 0; ct < 4; ++ct) {
        int cbase = ct * 64;
        __syncthreads();
        #pragma unroll
        for (int it = 0; it < 2; ++it) {
            int p = t + it * 256; int row = p >> 3, kc = (p & 7) * 8;
            *(uint4*)&ws_tile[row * 72 + kc] = *(const uint4*)(Wk16 + (size_t)(cbase + row) * 64 + kc);
        }
        __syncthreads();
        #pragma unroll
        for (int nsub = 0; nsub < 4; ++nsub) {
            bf16x8 w0 = *(const bf16x8*)&ws_tile[(nsub * 16 + lrow) * 72 + quad * 8];
            bf16x8 w1 = *(const bf16x8*)&ws_tile[(nsub * 16 + lrow) * 72 + 32 + quad * 8];
            f32x4 acc = {0.f, 0.f, 0.f, 0.f};
            acc = __builtin_amdgcn_mfma_f32_16x16x32_bf16(w0, a0, acc, 0, 0, 0);
            acc = __builtin_amdgcn_mfma_f32_16x16x32_bf16(w1, a1, acc, 0, 0, 0);
            float4 b4 = *(const float4*)(bkL + cbase + nsub * 16 + quad * 4);
            float f0 = (acc[0] + b4.x) * 16.f, f1 = (acc[1] + b4.y) * 16.f;
            float f2v = (acc[2] + b4.z) * 16.f, f3v = (acc[3] + b4.w) * 16.f;
            int pk = __builtin_amdgcn_cvt_pk_fp8_f32(f0, f1, 0, false);
            pk = __builtin_amdgcn_cvt_pk_fp8_f32(f2v, f3v, pk, true);
            int g = nsub * 4 + quad;
            *(unsigned int*)&kvst[nl * 144 + g * 8] = (unsigned int)pk;
        }
        __syncthreads();
        #pragma unroll
        for (int it = 0; it < 2; ++it) {
            int p = t + it * 256; int row = p >> 3, kc = (p & 7) * 8;
            *(uint4*)&ws_tile[row * 72 + kc] = *(const uint4*)(Wv16 + (size_t)(cbase + row) * 64 + kc);
        }
        __syncthreads();
        #pragma unroll
        for (int nsub = 0; nsub < 4; ++nsub) {
            bf16x8 w0 = *(const bf16x8*)&ws_tile[(nsub * 16 + lrow) * 72 + quad * 8];
            bf16x8 w1 = *(const bf16x8*)&ws_tile[(nsub * 16 + lrow) * 72 + 32 + quad * 8];
            f32x4 acc = {0.f, 0.f, 0.f, 0.f};
            acc = __builtin_amdgcn_mfma_f32_16x16x32_bf16(w0, a0, acc, 0, 0, 0);
            acc = __builtin_amdgcn_mfma_f32_16x16x32_bf16(w1, a1, acc, 0, 0, 0);
            float4 b4 = *(const float4*)(bvL + cbase + nsub * 16 + quad * 4);
            float f0 = (acc[0] + b4.x) * 16.f, f1 = (acc[1] + b4.y) * 16.f;
            float f2v = (acc[2] + b4.z) * 16.f, f3v = (acc[3] + b4.w) * 16.f;
            int pk = __builtin_amdgcn_cvt_pk_fp8_f32(f0, f1, 0, false);
            pk = __builtin_amdgcn_cvt_pk_fp8_f32(f2v, f3v, pk, true);
            int g = nsub * 4 + quad;
            *(unsigned int*)&kvst[nl * 144 + g * 8 + 4] = (unsigned int)pk;
        }
        __syncthreads();
        #pragma unroll
        for (int it = 0; it < 2; ++it) {
            int p = t + it * 256; int row = p >> 3, ch = p & 7;
            int grow = m0 + row;
            if (grow < N_NODES)
                *(uint4*)(kv + (size_t)grow * 512 + cbase * 2 + ch * 16) = *(const uint4*)&kvst[row * 144 + ch * 16];
        }
    }

    // ---- skip tile (fp32) ----
    {
        __syncthreads();
        #pragma unroll
        for (int it = 0; it < 2; ++it) {
            int p = t + it * 256; int row = p >> 3, kc = (p & 7) * 8;
            *(uint4*)&ws_tile[row * 72 + kc] = *(const uint4*)(Wsk16 + (size_t)row * 64 + kc);
        }
        __syncthreads();
        #pragma unroll
        for (int nsub = 0; nsub < 4; ++nsub) {
            bf16x8 w0 = *(const bf16x8*)&ws_tile[(nsub * 16 + lrow) * 72 + quad * 8];
            bf16x8 w1 = *(const bf16x8*)&ws_tile[(nsub * 16 + lrow) * 72 + 32 + quad * 8];
            f32x4 acc = {0.f, 0.f, 0.f, 0.f};
            acc = __builtin_amdgcn_mfma_f32_16x16x32_bf16(w0, a0, acc, 0, 0, 0);
            acc = __builtin_amdgcn_mfma_f32_16x16x32_bf16(w1, a1, acc, 0, 0, 0);
            float4 b4 = *(const float4*)(bskL + nsub * 16 + quad * 4);
            float4 o;
            o.x = acc[0] + b4.x; o.y = acc[1] + b4.y;
            o.z = acc[2] + b4.z; o.w = acc[3] + b4.w;
            *(float4*)&skst[nl * 68 + nsub * 16 + quad * 4] = o;
        }
        __syncthreads();
        int row = t >> 2, c0 = (t & 3) * 16;
        int grow = m0 + row;
        if (grow < N_NODES) {
            #pragma unroll
            for (int j = 0; j < 4; ++j)
                *(float4*)(skip + (size_t)grow * 64 + c0 + j * 4) = *(const float4*)&skst[row * 68 + c0 + j * 4];
        }
    }
}

// ---------------- Attention: round-6 body (unroll 4, fp8 kv) ----------------
__global__ __launch_bounds__(256) void attn_kernel(
    const u16* __restrict__ q, const u8* __restrict__ kv,
    const float* __restrict__ skip,
    const int* __restrict__ row_start, const int* __restrict__ csr_src,
    float* __restrict__ hout)
{
    int wave = threadIdx.x >> 6;
    int lane = threadIdx.x & 63;
    int n = blockIdx.x * 4 + wave;
    if (n >= N_NODES) return;
    ushort4 q4 = ((const ushort4*)(q + (size_t)n * 256))[lane];
    float qf0 = b2f(q4.x), qf1 = b2f(q4.y), qf2 = b2f(q4.z), qf3 = b2f(q4.w);
    const u8* kvl = kv + lane * 8;
    float l = 0.f;
    float a0 = 0.f, a1 = 0.f, a2 = 0.f, a3 = 0.f;
    int e0 = row_start[n], e1 = row_start[n + 1];
    for (int e = e0; e < e1; e += 4) {
        int rem = e1 - e;   // >= 1
        int i1 = rem > 1 ? e + 1 : e;
        int i2 = rem > 2 ? e + 2 : e;
        int i3 = rem > 3 ? e + 3 : e;
        int s0 = csr_src[e], s1 = csr_src[i1], s2 = csr_src[i2], s3 = csr_src[i3];
        uint2 c0 = *(const uint2*)(kvl + (size_t)s0 * 512);
        uint2 c1 = *(const uint2*)(kvl + (size_t)s1 * 512);
        uint2 c2 = *(const uint2*)(kvl + (size_t)s2 * 512);
        uint2 c3 = *(const uint2*)(kvl + (size_t)s3 * 512);
        f32x2 k0a = __builtin_amdgcn_cvt_pk_f32_fp8(c0.x, false), k0b = __builtin_amdgcn_cvt_pk_f32_fp8(c0.x, true);
        f32x2 k1a = __builtin_amdgcn_cvt_pk_f32_fp8(c1.x, false), k1b = __builtin_amdgcn_cvt_pk_f32_fp8(c1.x, true);
        f32x2 k2a = __builtin_amdgcn_cvt_pk_f32_fp8(c2.x, false), k2b = __builtin_amdgcn_cvt_pk_f32_fp8(c2.x, true);
        f32x2 k3a = __builtin_amdgcn_cvt_pk_f32_fp8(c3.x, false), k3b = __builtin_amdgcn_cvt_pk_f32_fp8(c3.x, true);
        float p0 = qf0 * k0a.x + qf1 * k0a.y + qf2 * k0b.x + qf3 * k0b.y;
        float p1 = qf0 * k1a.x + qf1 * k1a.y + qf2 * k1b.x + qf3 * k1b.y;
        float p2 = qf0 * k2a.x + qf1 * k2a.y + qf2 * k2b.x + qf3 * k2b.y;
        float p3 = qf0 * k3a.x + qf1 * k3a.y + qf2 * k3b.x + qf3 * k3b.y;
        p0 += __shfl_xor(p0, 1); p1 += __shfl_xor(p1, 1); p2 += __shfl_xor(p2, 1); p3 += __shfl_xor(p3, 1);
        p0 += __shfl_xor(p0, 2); p1 += __shfl_xor(p1, 2); p2 += __shfl_xor(p2, 2); p3 += __shfl_xor(p3, 2);
        p0 += __shfl_xor(p0, 4); p1 += __shfl_xor(p1, 4); p2 += __shfl_xor(p2, 4); p3 += __shfl_xor(p3, 4);
        p0 += __shfl_xor(p0, 8); p1 += __shfl_xor(p1, 8); p2 += __shfl_xor(p2, 8); p3 += __shfl_xor(p3, 8);
        const float S = 0.0078125f;  // 1/(8*16)
        float w0 = __expf(p0 * S);
        float w1 = rem > 1 ? __expf(p1 * S) : 0.f;
        float w2 = rem > 2 ? __expf(p2 * S) : 0.f;
        float w3 = rem > 3 ? __expf(p3 * S) : 0.f;
        l += (w0 + w1) + (w2 + w3);
        f32x2 v0a = __builtin_amdgcn_cvt_pk_f32_fp8(c0.y, false), v0b = __builtin_amdgcn_cvt_pk_f32_fp8(c0.y, true);
        f32x2 v1a = __builtin_amdgcn_cvt_pk_f32_fp8(c1.y, false), v1b = __builtin_amdgcn_cvt_pk_f32_fp8(c1.y, true);
        f32x2 v2a = __builtin_amdgcn_cvt_pk_f32_fp8(c2.y, false), v2b = __builtin_amdgcn_cvt_pk_f32_fp8(c2.y, true);
        f32x2 v3a = __builtin_amdgcn_cvt_pk_f32_fp8(c3.y, false), v3b = __builtin_amdgcn_cvt_pk_f32_fp8(c3.y, true);
        a0 += w0 * v0a.x + w1 * v1a.x + w2 * v2a.x + w3 * v3a.x;
        a1 += w0 * v0a.y + w1 * v1a.y + w2 * v2a.y + w3 * v3a.y;
        a2 += w0 * v0b.x + w1 * v1b.x + w2 * v2b.x + w3 * v3b.x;
        a3 += w0 * v0b.y + w1 * v1b.y + w2 * v2b.y + w3 * v3b.y;
    }
    float inv = l > 0.f ? 1.f / l : 0.f;
    a0 *= inv; a1 *= inv; a2 *= inv; a3 *= inv;
    a0 += __shfl_xor(a0, 16); a0 += __shfl_xor(a0, 32);
    a1 += __shfl_xor(a1, 16); a1 += __shfl_xor(a1, 32);
    a2 += __shfl_xor(a2, 16); a2 += __shfl_xor(a2, 32);
    a3 += __shfl_xor(a3, 16); a3 += __shfl_xor(a3, 32);
    if ((lane >> 4) == 0) {
        const float OS = 0.015625f;  // 0.25 (head mean) * 1/16 (v scale)
        float4 sk = ((const float4*)(skip + (size_t)n * 64))[lane];
        float4 o;
        o.x = elu_f(OS * a0 + sk.x);
        o.y = elu_f(OS * a1 + sk.y);
        o.z = elu_f(OS * a2 + sk.z);
        o.w = elu_f(OS * a3 + sk.w);
        ((float4*)(hout + (size_t)n * 64))[lane] = o;
    }
}

// ---------------- Output MLP: 64->64 elu (MFMA) ->32 elu (MFMA) ->8 (VALU) ----------------
__global__ __launch_bounds__(256) void mlp_kernel(const float* __restrict__ h,
    const float* __restrict__ w1, const float* __restrict__ b1,
    const float* __restrict__ w2, const float* __restrict__ b2,
    const float* __restrict__ w3, const float* __restrict__ b3,
    float* __restrict__ out)
{
    __shared__ u16 hs[64 * 72];
    __shared__ u16 w1s[64 * 72];
    __shared__ u16 t1s[64 * 72];
    __shared__ u16 w2s[32 * 72];
    __shared__ float t2s[64 * 33];
    __shared__ float w3s[8 * 33];
    __shared__ float b1s[64], b2s[32], b3s[8];
    int t = threadIdx.x;
    int m0 = blockIdx.x * 64;

    #pragma unroll
    for (int r = 0; r < 4; ++r) {
        int p = t + r * 256; int row = p >> 4, kc = (p & 15) * 4;
        float4 val = make_float4(0.f, 0.f, 0.f, 0.f);
        if (m0 + row < N_NODES) val = *(const float4*)(h + (size_t)(m0 + row) * 64 + kc);
        ushort4 u; u.x = f2b(val.x); u.y = f2b(val.y); u.z = f2b(val.z); u.w = f2b(val.w);
        *(ushort4*)&hs[row * 72 + kc] = u;
    }
    #pragma unroll
    for (int r = 0; r < 4; ++r) {
        int p = t + r * 256; int row = p >> 4, kc = (p & 15) * 4;
        float4 val = *(const float4*)(w1 + row * 64 + kc);
        ushort4 u; u.x = f2b(val.x); u.y = f2b(val.y); u.z = f2b(val.z); u.w = f2b(val.w);
        *(ushort4*)&w1s[row * 72 + kc] = u;
    }
    #pragma unroll
    for (int r = 0; r < 2; ++r) {
        int p = t + r * 256; int row = p >> 4, kc = (p & 15) * 4;
        float4 val = *(const float4*)(w2 + row * 64 + kc);
        ushort4 u; u.x = f2b(val.x); u.y = f2b(val.y); u.z = f2b(val.z); u.w = f2b(val.w);
        *(ushort4*)&w2s[row * 72 + kc] = u;
    }
    if (t < 8 * 32) { int r = t >> 5, c = t & 31; w3s[r * 33 + c] = w3[t]; }
    if (t < 64) b1s[t] = b1[t];
    if (t >= 64 && t < 96) b2s[t - 64] = b2[t - 64];
    if (t >= 96 && t < 104) b3s[t - 96] = b3[t - 96];
    __syncthreads();

    int wave = t >> 6, lane = t & 63;
    int lrow = lane & 15, quad = lane >> 4;
    int m_off = wave * 16;

    {
        bf16x8 a0 = *(const bf16x8*)&hs[(m_off + lrow) * 72 + quad * 8];
        bf16x8 a1 = *(const bf16x8*)&hs[(m_off + lrow) * 72 + 32 + quad * 8];
        #pragma unroll
        for (int nsub = 0; nsub < 4; ++nsub) {
            bf16x8 b0 = *(const bf16x8*)&w1s[(nsub * 16 + lrow) * 72 + quad * 8];
            bf16x8 b1v = *(const bf16x8*)&w1s[(nsub * 16 + lrow) * 72 + 32 + quad * 8];
            f32x4 acc = {0.f, 0.f, 0.f, 0.f};
            acc = __builtin_amdgcn_mfma_f32_16x16x32_bf16(a0, b0, acc, 0, 0, 0);
            acc = __builtin_amdgcn_mfma_f32_16x16x32_bf16(a1, b1v, acc, 0, 0, 0);
            int col = nsub * 16 + lrow;
            float bias = b1s[col];
            #pragma unroll
            for (int r = 0; r < 4; ++r) {
                int row = m_off + quad * 4 + r;
                t1s[row * 72 + col] = f2b(elu_f(acc[r] + bias));
            }
        }
    }
    __syncthreads();

    {
        bf16x8 a0 = *(const bf16x8*)&t1s[(m_off + lrow) * 72 + quad * 8];
        bf16x8 a1 = *(const bf16x8*)&t1s[(m_off + lrow) * 72 + 32 + quad * 8];
        #pragma unroll
        for (int nsub = 0; nsub < 2; ++nsub) {
            bf16x8 b0 = *(const bf16x8*)&w2s[(nsub * 16 + lrow) * 72 + quad * 8];
            bf16x8 b1v = *(const bf16x8*)&w2s[(nsub * 16 + lrow) * 72 + 32 + quad * 8];
            f32x4 acc = {0.f, 0.f, 0.f, 0.f};
            acc = __builtin_amdgcn_mfma_f32_16x16x32_bf16(a0, b0, acc, 0, 0, 0);
            acc = __builtin_amdgcn_mfma_f32_16x16x32_bf16(a1, b1v, acc, 0, 0, 0);
            int col = nsub * 16 + lrow;
            float bias = b2s[col];
            #pragma unroll
            for (int r = 0; r < 4; ++r) {
                int row = m_off + quad * 4 + r;
                t2s[row * 33 + col] = elu_f(acc[r] + bias);
            }
        }
    }
    __syncthreads();

    #pragma unroll
    for (int r = 0; r < 2; ++r) {
        int idx = t + r * 256;
        int node = idx >> 3, j = idx & 7;
        int row = m0 + node;
        if (row < N_NODES) {
            float acc = b3s[j];
            #pragma unroll
            for (int kk = 0; kk < 32; ++kk) acc += t2s[node * 33 + kk] * w3s[j * 33 + kk];
            out[(size_t)row * 8 + j] = acc;
        }
    }
}

extern "C" void kernel_launch(void* const* d_in, const int* in_sizes, int n_in,
                              void* d_out, int out_size, void* d_ws, size_t ws_size,
                              hipStream_t stream) {
    (void)in_sizes; (void)n_in; (void)out_size; (void)ws_size;
    const float* x   = (const float*)d_in[0];
    const int* ei    = (const int*)d_in[1];
    const float* ew1 = (const float*)d_in[2];
    const float* eb1 = (const float*)d_in[3];
    const float* ew2 = (const float*)d_in[4];
    const float* eb2 = (const float*)d_in[5];
    const float* Wq  = (const float*)d_in[6];
    const float* bq  = (const float*)d_in[7];
    const float* Wk  = (const float*)d_in[8];
    const float* bk  = (const float*)d_in[9];
    const float* Wv  = (const float*)d_in[10];
    const float* bv  = (const float*)d_in[11];
    const float* Wsk = (const float*)d_in[12];
    const float* bsk = (const float*)d_in[13];
    const float* ow1 = (const float*)d_in[14];
    const float* ob1 = (const float*)d_in[15];
    const float* ow2 = (const float*)d_in[16];
    const float* ob2 = (const float*)d_in[17];
    const float* ow3 = (const float*)d_in[18];
    const float* ob3 = (const float*)d_in[19];

    char* ws = (char*)d_ws;
    size_t off = 0;
    auto alloc = [&](size_t bytes) -> void* {
        void* p = ws + off;
        off += (bytes + 255) & ~(size_t)255;
        return p;
    };
    float* h0    = (float*)alloc((size_t)N_NODES * 64 * 4);
    float* h1    = (float*)alloc((size_t)N_NODES * 64 * 4);
    u16*   q     = (u16*)  alloc((size_t)N_NODES * 256 * 2);
    u8*    kv    = (u8*)   alloc((size_t)N_NODES * 512);
    float* skp   = (float*)alloc((size_t)N_NODES * 64 * 4);
    u16*   w16   = (u16*)  alloc((size_t)212992 * 2);
    int*   cnt   = (int*)  alloc((size_t)N_NODES * 4);
    int*   cursor= (int*)  alloc((size_t)N_NODES * 4);
    int*   rowst = (int*)  alloc((size_t)(N_NODES + 1) * 4);
    int*   csr   = (int*)  alloc((size_t)N_EDGES * 4);
    int*   bsum  = (int*)  alloc(512);
    int*   flag  = (int*)  alloc(256);

    u16* wq16  = w16;
    u16* wk16  = w16 + 65536;
    u16* wv16  = w16 + 131072;
    u16* wsk16 = w16 + 196608;

    const int NB = (N_NODES + 511) / 512;   // 98 scan blocks

    init_kernel<<<(N_NODES + 255) / 256, 256, 0, stream>>>(cnt, cursor);
    detect_kernel<<<1, 256, 0, stream>>>(ei, flag);
    wcvt_kernel<<<208, 256, 0, stream>>>(Wq, Wk, Wv, Wsk, w16);
    hist_kernel<<<(N_EDGES + 255) / 256, 256, 0, stream>>>(ei, flag, cnt);
    scan1_kernel<<<NB, 512, 0, stream>>>(cnt, rowst, bsum);
    scan2_kernel<<<1, 128, 0, stream>>>(bsum, rowst);
    scan3_kernel<<<NB, 512, 0, stream>>>(rowst, bsum);
    scatter_kernel<<<(N_EDGES + 255) / 256, 256, 0, stream>>>(ei, flag, rowst, cursor, csr);

    encoder_kernel<<<(N_NODES + 63) / 64, 256, 0, stream>>>(x, ew1, eb1, ew2, eb2, h0);

    float* hin = h0;
    float* hout = h1;
    for (int l = 0; l < 4; ++l) {
        proj_kernel<<<(N_NODES + 63) / 64, 256, 0, stream>>>(hin, wq16, wk16, wv16, wsk16,
                                                             bq, bk, bv, bsk, l, q, kv, skp);
        attn_kernel<<<(N_NODES + 3) / 4, 256, 0, stream>>>(q, kv, skp, rowst, csr, hout);
        float* tmp = hin; hin = hout; hout = tmp;
    }

    mlp_kernel<<<(N_NODES + 63) / 64, 256, 0, stream>>>(hin, ow1, ob1, ow2, ob2, ow3, ob3, (float*)d_out);
}